// Round 16
// baseline (212.559 us; speedup 1.0000x reference)
//
#include <hip/hip_runtime.h>
#include <hip/hip_fp16.h>
#include <math.h>

// Round 16: scan_kernel (85us) never actually held M0T in registers —
// VGPR_Count=100 < the 128 needed for V0..V31: the compiler SANK the
// loop-invariant loads into the loop (rematerialization), re-fetching 2KB
// M0T + G from L2 every step (~330cy/step of load latency, serial at 1
// wave/CU). Fix: load via inline-asm global_load_dwordx4/dword (opaque ->
// cannot be rematerialized), waves_per_eu(1,1), one vmcnt(0)+sched_barrier
// after the batch. Numerics bit-identical. All other kernels unchanged.

namespace {

constexpr float EPS = 1e-8f;

typedef _Float16 half8  __attribute__((ext_vector_type(8)));
typedef __fp16   fp16x2 __attribute__((ext_vector_type(2)));
typedef float    f32x4  __attribute__((ext_vector_type(4)));

__device__ __forceinline__ float sigmoidf_(float x) {
    return 1.0f / (1.0f + expf(-x));
}

#define RTREE64(p) do { \
    p += __shfl_xor(p, 32); p += __shfl_xor(p, 16); p += __shfl_xor(p, 8); \
    p += __shfl_xor(p, 4);  p += __shfl_xor(p, 2);  p += __shfl_xor(p, 1); } while (0)

#define RED32(p) do { \
    p += __shfl_xor(p, 16); p += __shfl_xor(p, 8); \
    p += __shfl_xor(p, 4);  p += __shfl_xor(p, 2);  p += __shfl_xor(p, 1); } while (0)

#define DPP_ADD(x, CTRL) \
    ((x) + __int_as_float(__builtin_amdgcn_mov_dpp( \
        __float_as_int(x), (CTRL), 0xF, 0xF, true)))
#define RDLANE(x, L) \
    __int_as_float(__builtin_amdgcn_readlane(__float_as_int(x), (L)))

#define REP32(F) F(0) F(1) F(2) F(3) F(4) F(5) F(6) F(7) \
                 F(8) F(9) F(10) F(11) F(12) F(13) F(14) F(15) \
                 F(16) F(17) F(18) F(19) F(20) F(21) F(22) F(23) \
                 F(24) F(25) F(26) F(27) F(28) F(29) F(30) F(31)

#define DOT8(A0, A1, B0, B1) \
    ((A0).x * (B0).x + (A0).y * (B0).y + (A0).z * (B0).z + (A0).w * (B0).w + \
     (A1).x * (B1).x + (A1).y * (B1).y + (A1).z * (B1).z + (A1).w * (B1).w)

#define PACK8(DST, U, W)                                           \
    do {                                                           \
        union { fp16x2 p[4]; uint4 q; } pk_;                       \
        pk_.p[0] = __builtin_amdgcn_cvt_pkrtz((U).x, (U).y);       \
        pk_.p[1] = __builtin_amdgcn_cvt_pkrtz((U).z, (U).w);       \
        pk_.p[2] = __builtin_amdgcn_cvt_pkrtz((W).x, (W).y);       \
        pk_.p[3] = __builtin_amdgcn_cvt_pkrtz((W).z, (W).w);       \
        *reinterpret_cast<uint4*>(DST) = pk_.q;                    \
    } while (0)

// ---------------- K1: prep (unchanged from r15) ----------------
__global__ void __launch_bounds__(256) prep_kernel(
    const float* __restrict__ sv, const float* __restrict__ sw,
    const float* __restrict__ snw, const float* __restrict__ def,
    const float* __restrict__ vnw,
    float* __restrict__ M0T, float* __restrict__ PD, float* __restrict__ G,
    float* __restrict__ w0s, float* __restrict__ iw0, float* __restrict__ iw1,
    float* __restrict__ n0, float* __restrict__ n1,
    float* __restrict__ nwv_g, float* __restrict__ DD_g)
{
    const int t = threadIdx.x, wave = t >> 6, lane = t & 63;
    __shared__ float wsum[39][4];

    if (blockIdx.x < 256) {
        const int c = blockIdx.x;
        const float w0v = sw[(size_t)c * 512 + t];
        const float w1v = sw[(size_t)c * 512 + 256 + t];
#pragma unroll
        for (int k = 0; k < 32; ++k) {
            float p = w0v * sv[k * 256 + t];
            RTREE64(p);
            if (lane == 0) wsum[k][wave] = p;
        }
#pragma unroll
        for (int j = 0; j < 4; ++j) {
            float p = w1v * def[j * 256 + t];
            RTREE64(p);
            if (lane == 0) wsum[32 + j][wave] = p;
        }
        {
            float p = w0v * w0v; RTREE64(p); if (lane == 0) wsum[36][wave] = p;
            float q = w1v * w1v; RTREE64(q); if (lane == 0) wsum[37][wave] = q;
            float r = w0v;       RTREE64(r); if (lane == 0) wsum[38][wave] = r;
        }
        __syncthreads();
        if (t < 32) {
            M0T[t * 256 + c] = wsum[t][0] + wsum[t][1] + wsum[t][2] + wsum[t][3];
        } else if (t < 36) {
            PD[(t - 32) * 256 + c] =
                wsum[t][0] + wsum[t][1] + wsum[t][2] + wsum[t][3];
        } else if (t == 36) {
            iw0[c] = 1.0f / fmaxf(sqrtf(wsum[36][0] + wsum[36][1] +
                                        wsum[36][2] + wsum[36][3]), EPS);
        } else if (t == 37) {
            iw1[c] = 1.0f / fmaxf(sqrtf(wsum[37][0] + wsum[37][1] +
                                        wsum[37][2] + wsum[37][3]), EPS);
        } else if (t == 38) {
            w0s[c] = wsum[38][0] + wsum[38][1] + wsum[38][2] + wsum[38][3];
        } else if (t == 39) {
            n0[c] = sigmoidf_(snw[2 * c]);
        } else if (t == 40) {
            n1[c] = sigmoidf_(snw[2 * c + 1]);
        }
    } else if (blockIdx.x < 288) {
        const int k = blockIdx.x - 256;
        const float svk = sv[k * 256 + t];
#pragma unroll
        for (int m = 0; m < 32; ++m) {
            float p = svk * sv[m * 256 + t];
            RTREE64(p);
            if (lane == 0) wsum[m][wave] = p;
        }
        __syncthreads();
        if (t < 32)
            G[k * 32 + t] = wsum[t][0] + wsum[t][1] + wsum[t][2] + wsum[t][3];
    } else {
        const float dv0 = def[t], dv1 = def[256 + t];
        const float dv2 = def[512 + t], dv3 = def[768 + t];
        float dv[4] = {dv0, dv1, dv2, dv3};
#pragma unroll
        for (int i = 0; i < 4; ++i) {
#pragma unroll
            for (int j = 0; j < 4; ++j) {
                float p = dv[i] * dv[j];
                RTREE64(p);
                if (lane == 0) wsum[i * 4 + j][wave] = p;
            }
        }
        __syncthreads();
        if (t < 16)
            DD_g[t] = wsum[t][0] + wsum[t][1] + wsum[t][2] + wsum[t][3];
        if (t >= 32 && t < 50)
            nwv_g[t - 32] = sigmoidf_(vnw[t - 32]);
    }
}

// ---------------- K2: stats + cvt (unchanged from r15) ----------------
__global__ void __launch_bounds__(256) stats_kernel(
    const float* __restrict__ x, const float* __restrict__ y,
    const float* __restrict__ av_g, const float* __restrict__ xn_g,
    const float* __restrict__ yn_g, const float* __restrict__ def,
    const float* __restrict__ sw, const float* __restrict__ nwv_g,
    const float* __restrict__ DD_g,
    __half* __restrict__ xh, __half* __restrict__ yh,
    __half* __restrict__ swh, float* __restrict__ coef_g)
{
    const int blk = blockIdx.x;
    const int t   = threadIdx.x;

    if (blk >= 4096) {   // sw (k=1) fp16 tail
        const size_t j = ((size_t)(blk - 4096) * 256 + t) * 8;
        const int c = (int)(j >> 8), k = (int)(j & 255);
        const float* src = sw + (size_t)c * 512 + 256 + k;
        const float4 u = *(const float4*)(src);
        const float4 w = *(const float4*)(src + 4);
        PACK8(swh + j, u, w);
        return;
    }

    const int seg = t >> 5;
    const int li  = t & 31;
    const int m   = blk * 8 + seg;
    const int v0  = li * 8;
    const size_t base = (size_t)m * 256 + v0;

    const float4 xa = *(const float4*)(x + base);
    const float4 xb = *(const float4*)(x + base + 4);
    const float4 ya = *(const float4*)(y + base);
    const float4 yb = *(const float4*)(y + base + 4);
    const float4 aa = *(const float4*)(av_g + base);
    const float4 ab = *(const float4*)(av_g + base + 4);
    const float4 na = *(const float4*)(xn_g + base);
    const float4 nb = *(const float4*)(xn_g + base + 4);
    const float4 ma = *(const float4*)(yn_g + base);
    const float4 mb = *(const float4*)(yn_g + base + 4);

    PACK8(xh + base, xa, xb);
    PACK8(yh + base, ya, yb);

    float r0 = DOT8(aa, ab, na, nb);
    float r1 = DOT8(aa, ab, ma, mb);
    float r2 = DOT8(na, nb, ma, mb);
    float r3 = DOT8(aa, ab, aa, ab);
    float r4 = DOT8(na, nb, na, nb);
    float r5 = DOT8(ma, mb, ma, mb);
    float r6 = DOT8(xa, xb, xa, xb);
    float r7 = DOT8(ya, yb, ya, yb);
    float r8 = DOT8(xa, xb, ya, yb);
    float r9, r10, r11, r12, r13, r14, r15, r16;
    {
        const float4 d0a = *(const float4*)(def + v0);
        const float4 d0b = *(const float4*)(def + v0 + 4);
        r9  = DOT8(xa, xb, d0a, d0b);  r13 = DOT8(ya, yb, d0a, d0b);
        const float4 d1a = *(const float4*)(def + 256 + v0);
        const float4 d1b = *(const float4*)(def + 256 + v0 + 4);
        r10 = DOT8(xa, xb, d1a, d1b);  r14 = DOT8(ya, yb, d1a, d1b);
        const float4 d2a = *(const float4*)(def + 512 + v0);
        const float4 d2b = *(const float4*)(def + 512 + v0 + 4);
        r11 = DOT8(xa, xb, d2a, d2b);  r15 = DOT8(ya, yb, d2a, d2b);
        const float4 d3a = *(const float4*)(def + 768 + v0);
        const float4 d3b = *(const float4*)(def + 768 + v0 + 4);
        r12 = DOT8(xa, xb, d3a, d3b);  r16 = DOT8(ya, yb, d3a, d3b);
    }
    RED32(r0);  RED32(r1);  RED32(r2);  RED32(r3);  RED32(r4);  RED32(r5);
    RED32(r6);  RED32(r7);  RED32(r8);  RED32(r9);  RED32(r10); RED32(r11);
    RED32(r12); RED32(r13); RED32(r14); RED32(r15); RED32(r16);

    const float nav = fmaxf(sqrtf(r3), EPS);
    const float nxn = fmaxf(sqrtf(r4), EPS);
    const float nyn = fmaxf(sqrtf(r5), EPS);
    float cs[3];
    cs[0] = r0 / (nav * nxn);
    cs[1] = r1 / (nav * nyn);
    cs[2] = r2 / (nxn * nyn);

    float vc[6];
#pragma unroll
    for (int jj = 0; jj < 6; ++jj) {
        float p = 1.0f;
#pragma unroll
        for (int k = 0; k < 3; ++k) {
            const float a = nwv_g[jj * 3 + k];
            p = p * (a * cs[k] + (1.0f - a) * (1.0f - cs[k]));
        }
        vc[jj] = p;
    }

    float val2 = vc[0] * vc[0] * r6 + vc[1] * vc[1] * r7
               + 2.0f * vc[0] * vc[1] * r8;
    const float sx = vc[2] * r9  + vc[3] * r10 + vc[4] * r11 + vc[5] * r12;
    const float sy = vc[2] * r13 + vc[3] * r14 + vc[4] * r15 + vc[5] * r16;
    val2 += 2.0f * vc[0] * sx + 2.0f * vc[1] * sy;
#pragma unroll
    for (int i2 = 0; i2 < 4; ++i2) {
#pragma unroll
        for (int j2 = 0; j2 < 4; ++j2) {
            val2 += vc[2 + i2] * vc[2 + j2] * DD_g[i2 * 4 + j2];
        }
    }
    const float inv_val = 1.0f / fmaxf(sqrtf(val2), EPS);

    if (li == 0) {
        const float4 cA = {vc[0] * inv_val, vc[1] * inv_val,
                           vc[2] * inv_val, vc[3] * inv_val};
        const float4 cB = {vc[4] * inv_val, vc[5] * inv_val, 0.f, 0.f};
        *(float4*)(coef_g + (size_t)m * 8)     = cA;
        *(float4*)(coef_g + (size_t)m * 8 + 4) = cB;
    }
}

// ---------------- K3: PXY GEMM (unchanged from r14) ----------------
__global__ void __launch_bounds__(256) pxy_gemm(
    const __half* __restrict__ xh, const __half* __restrict__ yh,
    const __half* __restrict__ swh, __half* __restrict__ pxy)
{
    const int swz      = (blockIdx.x & 7) * 256 + (blockIdx.x >> 3);
    const int cstrip   = swz & 7;
    const int rowblock = swz >> 3;
    const int wid  = threadIdx.x >> 6;
    const int lane = threadIdx.x & 63;
    const int l16  = lane & 15;
    const int lhi  = lane >> 4;
    const bool isx = rowblock < 128;
    const __half* __restrict__ A = isx ? xh : yh;
    const int row0   = (isx ? rowblock : rowblock - 128) * 256 + wid * 64;
    const int cbase  = cstrip * 32;
    const int colout = isx ? 0 : 256;

    const f32x4 z = {0.f, 0.f, 0.f, 0.f};
    f32x4 acc00 = z, acc01 = z, acc10 = z, acc11 = z;
    f32x4 acc20 = z, acc21 = z, acc30 = z, acc31 = z;

    const __half* arow = A   + (size_t)(row0 + l16) * 256;
    const __half* brow = swh + (size_t)(cbase + l16) * 256;

#pragma unroll
    for (int k0 = 0; k0 < 256; k0 += 32) {
        const int ka = k0 + lhi * 8;
        const half8 a0 = *(const half8*)(arow + ka);
        const half8 a1 = *(const half8*)(arow + 16 * 256 + ka);
        const half8 a2 = *(const half8*)(arow + 32 * 256 + ka);
        const half8 a3 = *(const half8*)(arow + 48 * 256 + ka);
        const half8 b0 = *(const half8*)(brow + ka);
        const half8 b1 = *(const half8*)(brow + 16 * 256 + ka);
        acc00 = __builtin_amdgcn_mfma_f32_16x16x32_f16(a0, b0, acc00, 0, 0, 0);
        acc01 = __builtin_amdgcn_mfma_f32_16x16x32_f16(a0, b1, acc01, 0, 0, 0);
        acc10 = __builtin_amdgcn_mfma_f32_16x16x32_f16(a1, b0, acc10, 0, 0, 0);
        acc11 = __builtin_amdgcn_mfma_f32_16x16x32_f16(a1, b1, acc11, 0, 0, 0);
        acc20 = __builtin_amdgcn_mfma_f32_16x16x32_f16(a2, b0, acc20, 0, 0, 0);
        acc21 = __builtin_amdgcn_mfma_f32_16x16x32_f16(a2, b1, acc21, 0, 0, 0);
        acc30 = __builtin_amdgcn_mfma_f32_16x16x32_f16(a3, b0, acc30, 0, 0, 0);
        acc31 = __builtin_amdgcn_mfma_f32_16x16x32_f16(a3, b1, acc31, 0, 0, 0);
    }

    const int colp = (((colout + cbase) >> 5) << 4) + l16;   // col'
#define STPAIR(ACCA, ACCB, ROFF)                                          \
    do {                                                                  \
        union { fp16x2 p[4]; uint4 u; } pk;                               \
        pk.p[0] = __builtin_amdgcn_cvt_pkrtz((ACCA)[0], (ACCA)[1]);       \
        pk.p[1] = __builtin_amdgcn_cvt_pkrtz((ACCA)[2], (ACCA)[3]);       \
        pk.p[2] = __builtin_amdgcn_cvt_pkrtz((ACCB)[0], (ACCB)[1]);       \
        pk.p[3] = __builtin_amdgcn_cvt_pkrtz((ACCB)[2], (ACCB)[3]);       \
        const size_t hb = (size_t)(((row0 + (ROFF)) >> 2) + lhi) * 2048   \
                        + (size_t)colp * 8;                               \
        *reinterpret_cast<uint4*>(pxy + hb) = pk.u;                       \
    } while (0)
    STPAIR(acc00, acc01, 0);
    STPAIR(acc10, acc11, 16);
    STPAIR(acc20, acc21, 32);
    STPAIR(acc30, acc31, 48);
#undef STPAIR
}

// ---------------- K4: finish-lite (unchanged from r15) ----------------
__device__ __forceinline__ float half_of(uint2 u, int j) {
    const unsigned w = (j < 2) ? u.x : u.y;
    const unsigned sh = (unsigned)(j & 1) * 16u;
    return __half2float(__ushort_as_half((unsigned short)(w >> sh)));
}

__global__ void __launch_bounds__(256) finish_kernel(
    const float* __restrict__ coef_g, const float* __restrict__ PD_g,
    const float* __restrict__ iw1_g, const float* __restrict__ n1_g,
    const __half* __restrict__ pxy, float* __restrict__ i1_g)
{
    const int mg = blockIdx.x;
    const int t = threadIdx.x;

    const int cpx = ((t >> 5) << 4) + (t & 15);
    const int ppx = (t >> 4) & 1;
    const size_t gb = (size_t)mg * 2048;
    const uint2 upx = *reinterpret_cast<const uint2*>(
        pxy + gb + (size_t)cpx * 8 + ppx * 4);
    const uint2 upy = *reinterpret_cast<const uint2*>(
        pxy + gb + (size_t)(128 + cpx) * 8 + ppx * 4);

    const float pd0 = PD_g[t],        pd1 = PD_g[256 + t];
    const float pd2 = PD_g[512 + t],  pd3 = PD_g[768 + t];
    const float iw1v = iw1_g[t];
    const float n1v  = n1_g[t];
    const float An = 2.0f * n1v - 1.0f;
    const float Bn = 1.0f - n1v;

#pragma unroll
    for (int j = 0; j < 4; ++j) {
        const int m = 4 * mg + j;
        const float4 cA = *(const float4*)(coef_g + (size_t)m * 8);
        const float2 cB = *(const float2*)(coef_g + (size_t)m * 8 + 4);
        const float px = half_of(upx, j);
        const float py = half_of(upy, j);
        const float d1s = cA.x * px + cA.y * py
                        + cA.z * pd0 + cA.w * pd1 + cB.x * pd2 + cB.y * pd3;
        float c1 = d1s * iw1v;
        c1 = fmaxf(c1, 0.01f * c1);
        i1_g[(size_t)m * 256 + t] = fmaf(c1, An, Bn);
    }
}

// ---------------- K5: the scan — asm-pinned register-resident M0T/G ----------------
__global__ void __launch_bounds__(64)
__attribute__((amdgpu_waves_per_eu(1, 1)))
scan_kernel(
    const float* __restrict__ i1_g, const float* __restrict__ M0T_g,
    const float* __restrict__ G_g, const float* __restrict__ w0s_g,
    const float* __restrict__ iw0_g, const float* __restrict__ n0_g,
    float* __restrict__ gws_g)
{
    const int b = blockIdx.x;
    const int L = threadIdx.x;              // owns c = 4L..4L+3
    const int mcol = L >> 1;                // G/h column (pairs share)

    // M0T columns via inline-asm loads: opaque to the compiler -> cannot be
    // rematerialized into the loop (round-15 failure: VGPR=100, loads sunk).
#define LV(K) float4 V##K;                                              \
    asm volatile("global_load_dwordx4 %0, %1, off"                     \
                 : "=v"(V##K) : "v"(M0T_g + (K) * 256 + 4 * L));
    REP32(LV)
#undef LV
#define LG(K) float GK##K;                                              \
    asm volatile("global_load_dword %0, %1, off"                       \
                 : "=v"(GK##K) : "v"(G_g + (K) * 32 + mcol));
    REP32(LG)
#undef LG
    asm volatile("s_waitcnt vmcnt(0)");
    __builtin_amdgcn_sched_barrier(0);

    const float4 w0s4 = *(const float4*)(w0s_g + 4 * L);
    const float4 iw4  = *(const float4*)(iw0_g + 4 * L);
    const float4 n04  = *(const float4*)(n0_g + 4 * L);
    const float4 di = {1e-6f * w0s4.x, 1e-6f * w0s4.y,
                       1e-6f * w0s4.z, 1e-6f * w0s4.w};
    const float4 An = {2.f * n04.x - 1.f, 2.f * n04.y - 1.f,
                       2.f * n04.z - 1.f, 2.f * n04.w - 1.f};
    const float4 Bn = {1.f - n04.x, 1.f - n04.y, 1.f - n04.z, 1.f - n04.w};

    float4 iA = *(const float4*)(i1_g + ((size_t)0 * 256 + b) * 256 + 4 * L);
    float4 iB = *(const float4*)(i1_g + ((size_t)1 * 256 + b) * 256 + 4 * L);
    float4 iC = *(const float4*)(i1_g + ((size_t)2 * 256 + b) * 256 + 4 * L);

    float gwv;   // loop-carried: lanes 2k,2k+1 hold gw[k]

#define NAND_GW(D0, D1, D2, D3, INV, IC)                              \
    do {                                                              \
        float cc0 = (D0) * (INV) * iw4.x; cc0 = fmaxf(cc0, 0.01f * cc0); \
        float cc1 = (D1) * (INV) * iw4.y; cc1 = fmaxf(cc1, 0.01f * cc1); \
        float cc2 = (D2) * (INV) * iw4.z; cc2 = fmaxf(cc2, 0.01f * cc2); \
        float cc3 = (D3) * (INV) * iw4.w; cc3 = fmaxf(cc3, 0.01f * cc3); \
        const float ch0 = fmaf(cc0, An.x, Bn.x) * (IC).x;             \
        const float ch1 = fmaf(cc1, An.y, Bn.y) * (IC).y;             \
        const float ch2 = fmaf(cc2, An.z, Bn.z) * (IC).z;             \
        const float ch3 = fmaf(cc3, An.w, Bn.w) * (IC).w;             \
        const float s4 = (ch0 + ch1) + (ch2 + ch3);                   \
        gwv = DPP_ADD(s4, 0xB1);  /* quad_perm xor1: pair sum */      \
    } while (0)

    // ---- step 0 ----
    {
        const float inv_rs = 1.0f / fmaxf(sqrtf(2.56e-10f), EPS);
        NAND_GW(di.x, di.y, di.z, di.w, inv_rs, iA);
        if ((L & 1) == 0) gws_g[(size_t)b * 32 + mcol] = gwv;
    }

    for (int s = 1; s < 128; ++s) {
        const int sp = (s + 2 < 128) ? s + 2 : 127;
        const float4 iN = *(const float4*)(
            i1_g + ((size_t)sp * 256 + b) * 256 + 4 * L);

#define RL(K) const float sg##K = RDLANE(gwv, 2 * (K));
        REP32(RL)
#undef RL

        float d0 = 0.f, d1 = 0.f, d2 = 0.f, d3 = 0.f, h = 0.f;
#define STEP_K(K)                                   \
        d0 = fmaf(V##K.x, sg##K, d0);               \
        d1 = fmaf(V##K.y, sg##K, d1);               \
        d2 = fmaf(V##K.z, sg##K, d2);               \
        d3 = fmaf(V##K.w, sg##K, d3);               \
        h  = fmaf(GK##K, sg##K, h);
        REP32(STEP_K)
#undef STEP_K

        float rp = h * gwv;
        rp = DPP_ADD(rp, 0x128);   // row_ror:8
        rp = DPP_ADD(rp, 0x124);   // row_ror:4
        rp = DPP_ADD(rp, 0x122);   // row_ror:2
        rp = DPP_ADD(rp, 0x121);   // row_ror:1
        const float rs2 = 0.5f * (RDLANE(rp, 0) + RDLANE(rp, 16) +
                                  RDLANE(rp, 32) + RDLANE(rp, 48));
        const float inv_rs = 1.0f / fmaxf(sqrtf(rs2), EPS);

        NAND_GW(d0, d1, d2, d3, inv_rs, iB);
        if ((L & 1) == 0)
            gws_g[((size_t)s * 256 + b) * 32 + mcol] = gwv;

        iB = iC; iC = iN;
    }
#undef NAND_GW
}

// ---------------- K6: expand (unchanged) ----------------
__global__ void __launch_bounds__(256) expand_kernel(
    const float* __restrict__ gws_g, const float* __restrict__ sv_g,
    float* __restrict__ out)
{
    const int t = threadIdx.x;
    const int m0 = blockIdx.x * 32;
    __shared__ __align__(16) float SvT[256 * 36];
    __shared__ __align__(16) float gwl[32 * 32];

    for (int i = t; i < 8192; i += 256) {
        const int k = i >> 8, v = i & 255;
        SvT[v * 36 + k] = sv_g[i];
    }
    for (int i = t; i < 1024; i += 256)
        gwl[i] = gws_g[(size_t)m0 * 32 + i];
    __syncthreads();

#pragma unroll 4
    for (int r = 0; r < 32; ++r) {
        float acc = 0.f;
#pragma unroll
        for (int j = 0; j < 8; ++j) {
            const float4 g   = *(const float4*)(gwl + r * 32 + 4 * j);
            const float4 sv4 = *(const float4*)(SvT + t * 36 + 4 * j);
            acc += g.x * sv4.x + g.y * sv4.y + g.z * sv4.z + g.w * sv4.w;
        }
        const int m = m0 + r;
        const int s = m >> 8, bb = m & 255;
        out[((size_t)bb * 128 + s) * 256 + t] = acc;
    }
}

} // namespace

extern "C" void kernel_launch(void* const* d_in, const int* in_sizes, int n_in,
                              void* d_out, int out_size, void* d_ws, size_t ws_size,
                              hipStream_t stream) {
    (void)in_sizes; (void)n_in; (void)out_size; (void)ws_size;
    const float* av  = (const float*)d_in[0];
    const float* xnm = (const float*)d_in[1];
    const float* x   = (const float*)d_in[2];
    const float* ynm = (const float*)d_in[3];
    const float* y   = (const float*)d_in[4];
    const float* sv  = (const float*)d_in[5];
    const float* sw  = (const float*)d_in[6];
    const float* snw = (const float*)d_in[7];
    const float* def = (const float*)d_in[8];
    const float* vnw = (const float*)d_in[9];

    __half* pxy = (__half*)d_ws;
    float*  i1  = (float*)((char*)d_ws + (size_t)33554432);
    float*  gws = i1 + 8388608;
    float*  sm  = gws + 1048576;
    float* M0T = sm;            // 8192
    float* PD  = M0T + 8192;    // 1024
    float* G   = PD + 1024;     // 1024
    float* w0s = G + 1024;      // 256
    float* iw0 = w0s + 256;
    float* iw1 = iw0 + 256;
    float* n0  = iw1 + 256;
    float* n1  = n0 + 256;
    __half* M0Th = (__half*)(n1 + 256);   // (unused; kept for layout)
    __half* swh  = M0Th + 8192;           // 65536 halfs (W1 fp16)
    float* nwvS  = (float*)(swh + 65536);
    float* DDs   = nwvS + 32;
    float* coef  = DDs + 32;
    __half* xh = (__half*)i1;             // alias: dead after pxy_gemm
    __half* yh = xh + 8388608;

    prep_kernel<<<dim3(289), dim3(256), 0, stream>>>(
        sv, sw, snw, def, vnw, M0T, PD, G, w0s, iw0, iw1, n0, n1, nwvS, DDs);
    stats_kernel<<<dim3(4128), dim3(256), 0, stream>>>(
        x, y, av, xnm, ynm, def, sw, nwvS, DDs, xh, yh, swh, coef);
    pxy_gemm<<<dim3(2048), dim3(256), 0, stream>>>(xh, yh, swh, pxy);
    finish_kernel<<<dim3(8192), dim3(256), 0, stream>>>(
        coef, PD, iw1, n1, pxy, i1);
    scan_kernel<<<dim3(256), dim3(64), 0, stream>>>(
        i1, M0T, G, w0s, iw0, n0, gws);
    expand_kernel<<<dim3(1024), dim3(256), 0, stream>>>(gws, sv, (float*)d_out);
}

// Round 17
// 192.933 us; speedup vs baseline: 1.1017x; 1.1017x over previous
//
#include <hip/hip_runtime.h>
#include <hip/hip_fp16.h>
#include <math.h>

// Round 17: r16 proved the allocator CAPS this kernel ~128-132 VGPR and
// SPILLS asm outputs beyond it (VGPR 100->132, dur unchanged 85us). Fix:
// shrink resident state to fit UNDER the cap instead of fighting it:
//  - M0T as fp16 k-pairs in 16 uint4 (64 VGPR, was 128); G as 16 packed
//    fp16 pairs (16 VGPR, was 32). Total ~120 <= cap -> no spill motive.
//  - gw broadcast: 1 DPP quad_perm[2,3,0,1] + 1 cvt_pkrtz + 16 readlanes
//    (was 32) -> 16 packed-fp16 SGPRs.
//  - dot section: 80 v_dot2_f32_f16 (2 MAC/instr, sgpr B operand) vs 160 FMA.
// prep emits the M0T pair layout into the old M0Th slot. Numerics: M0T fp16
// proven (r7-9); new gw/G fp16 roundings expected ~2-4e-3 < 6.6e-3 threshold.

namespace {

constexpr float EPS = 1e-8f;

typedef _Float16 half8  __attribute__((ext_vector_type(8)));
typedef __fp16   fp16x2 __attribute__((ext_vector_type(2)));
typedef float    f32x4  __attribute__((ext_vector_type(4)));

__device__ __forceinline__ float sigmoidf_(float x) {
    return 1.0f / (1.0f + expf(-x));
}

#define RTREE64(p) do { \
    p += __shfl_xor(p, 32); p += __shfl_xor(p, 16); p += __shfl_xor(p, 8); \
    p += __shfl_xor(p, 4);  p += __shfl_xor(p, 2);  p += __shfl_xor(p, 1); } while (0)

#define RED32(p) do { \
    p += __shfl_xor(p, 16); p += __shfl_xor(p, 8); \
    p += __shfl_xor(p, 4);  p += __shfl_xor(p, 2);  p += __shfl_xor(p, 1); } while (0)

#define DPP_ADD(x, CTRL) \
    ((x) + __int_as_float(__builtin_amdgcn_mov_dpp( \
        __float_as_int(x), (CTRL), 0xF, 0xF, true)))
#define DPP_MOVF(x, CTRL) \
    __int_as_float(__builtin_amdgcn_mov_dpp(__float_as_int(x), (CTRL), 0xF, 0xF, true))
#define RDLANE(x, L) \
    __int_as_float(__builtin_amdgcn_readlane(__float_as_int(x), (L)))

#define REP32(F) F(0) F(1) F(2) F(3) F(4) F(5) F(6) F(7) \
                 F(8) F(9) F(10) F(11) F(12) F(13) F(14) F(15) \
                 F(16) F(17) F(18) F(19) F(20) F(21) F(22) F(23) \
                 F(24) F(25) F(26) F(27) F(28) F(29) F(30) F(31)
#define REP16(F) F(0) F(1) F(2) F(3) F(4) F(5) F(6) F(7) \
                 F(8) F(9) F(10) F(11) F(12) F(13) F(14) F(15)

#define DOT8(A0, A1, B0, B1) \
    ((A0).x * (B0).x + (A0).y * (B0).y + (A0).z * (B0).z + (A0).w * (B0).w + \
     (A1).x * (B1).x + (A1).y * (B1).y + (A1).z * (B1).z + (A1).w * (B1).w)

#define PACK8(DST, U, W)                                           \
    do {                                                           \
        union { fp16x2 p[4]; uint4 q; } pk_;                       \
        pk_.p[0] = __builtin_amdgcn_cvt_pkrtz((U).x, (U).y);       \
        pk_.p[1] = __builtin_amdgcn_cvt_pkrtz((U).z, (U).w);       \
        pk_.p[2] = __builtin_amdgcn_cvt_pkrtz((W).x, (W).y);       \
        pk_.p[3] = __builtin_amdgcn_cvt_pkrtz((W).z, (W).w);       \
        *reinterpret_cast<uint4*>(DST) = pk_.q;                    \
    } while (0)

__device__ __forceinline__ unsigned pk2u(float a, float b) {
    union { fp16x2 p; unsigned u; } cv;
    cv.p = __builtin_amdgcn_cvt_pkrtz(a, b);
    return cv.u;
}

// ---------------- K1: prep (emits M0T fp16-pair layout) ----------------
__global__ void __launch_bounds__(256) prep_kernel(
    const float* __restrict__ sv, const float* __restrict__ sw,
    const float* __restrict__ snw, const float* __restrict__ def,
    const float* __restrict__ vnw,
    float* __restrict__ M0T, unsigned* __restrict__ M0Tp,
    float* __restrict__ PD, float* __restrict__ G,
    float* __restrict__ w0s, float* __restrict__ iw0, float* __restrict__ iw1,
    float* __restrict__ n0, float* __restrict__ n1,
    float* __restrict__ nwv_g, float* __restrict__ DD_g)
{
    const int t = threadIdx.x, wave = t >> 6, lane = t & 63;
    __shared__ float wsum[39][4];

    if (blockIdx.x < 256) {
        const int c = blockIdx.x;
        const float w0v = sw[(size_t)c * 512 + t];
        const float w1v = sw[(size_t)c * 512 + 256 + t];
#pragma unroll
        for (int k = 0; k < 32; ++k) {
            float p = w0v * sv[k * 256 + t];
            RTREE64(p);
            if (lane == 0) wsum[k][wave] = p;
        }
#pragma unroll
        for (int j = 0; j < 4; ++j) {
            float p = w1v * def[j * 256 + t];
            RTREE64(p);
            if (lane == 0) wsum[32 + j][wave] = p;
        }
        {
            float p = w0v * w0v; RTREE64(p); if (lane == 0) wsum[36][wave] = p;
            float q = w1v * w1v; RTREE64(q); if (lane == 0) wsum[37][wave] = q;
            float r = w0v;       RTREE64(r); if (lane == 0) wsum[38][wave] = r;
        }
        __syncthreads();
        if (t < 32) {
            const float v = wsum[t][0] + wsum[t][1] + wsum[t][2] + wsum[t][3];
            M0T[t * 256 + c] = v;
            const float vn = __shfl_down(v, 1);   // valid at even t
            if ((t & 1) == 0)
                M0Tp[c * 16 + (t >> 1)] = pk2u(v, vn);
        } else if (t < 36) {
            PD[(t - 32) * 256 + c] =
                wsum[t][0] + wsum[t][1] + wsum[t][2] + wsum[t][3];
        } else if (t == 36) {
            iw0[c] = 1.0f / fmaxf(sqrtf(wsum[36][0] + wsum[36][1] +
                                        wsum[36][2] + wsum[36][3]), EPS);
        } else if (t == 37) {
            iw1[c] = 1.0f / fmaxf(sqrtf(wsum[37][0] + wsum[37][1] +
                                        wsum[37][2] + wsum[37][3]), EPS);
        } else if (t == 38) {
            w0s[c] = wsum[38][0] + wsum[38][1] + wsum[38][2] + wsum[38][3];
        } else if (t == 39) {
            n0[c] = sigmoidf_(snw[2 * c]);
        } else if (t == 40) {
            n1[c] = sigmoidf_(snw[2 * c + 1]);
        }
    } else if (blockIdx.x < 288) {
        const int k = blockIdx.x - 256;
        const float svk = sv[k * 256 + t];
#pragma unroll
        for (int m = 0; m < 32; ++m) {
            float p = svk * sv[m * 256 + t];
            RTREE64(p);
            if (lane == 0) wsum[m][wave] = p;
        }
        __syncthreads();
        if (t < 32)
            G[k * 32 + t] = wsum[t][0] + wsum[t][1] + wsum[t][2] + wsum[t][3];
    } else {
        const float dv0 = def[t], dv1 = def[256 + t];
        const float dv2 = def[512 + t], dv3 = def[768 + t];
        float dv[4] = {dv0, dv1, dv2, dv3};
#pragma unroll
        for (int i = 0; i < 4; ++i) {
#pragma unroll
            for (int j = 0; j < 4; ++j) {
                float p = dv[i] * dv[j];
                RTREE64(p);
                if (lane == 0) wsum[i * 4 + j][wave] = p;
            }
        }
        __syncthreads();
        if (t < 16)
            DD_g[t] = wsum[t][0] + wsum[t][1] + wsum[t][2] + wsum[t][3];
        if (t >= 32 && t < 50)
            nwv_g[t - 32] = sigmoidf_(vnw[t - 32]);
    }
}

// ---------------- K2: stats + cvt (unchanged from r15) ----------------
__global__ void __launch_bounds__(256) stats_kernel(
    const float* __restrict__ x, const float* __restrict__ y,
    const float* __restrict__ av_g, const float* __restrict__ xn_g,
    const float* __restrict__ yn_g, const float* __restrict__ def,
    const float* __restrict__ sw, const float* __restrict__ nwv_g,
    const float* __restrict__ DD_g,
    __half* __restrict__ xh, __half* __restrict__ yh,
    __half* __restrict__ swh, float* __restrict__ coef_g)
{
    const int blk = blockIdx.x;
    const int t   = threadIdx.x;

    if (blk >= 4096) {   // sw (k=1) fp16 tail
        const size_t j = ((size_t)(blk - 4096) * 256 + t) * 8;
        const int c = (int)(j >> 8), k = (int)(j & 255);
        const float* src = sw + (size_t)c * 512 + 256 + k;
        const float4 u = *(const float4*)(src);
        const float4 w = *(const float4*)(src + 4);
        PACK8(swh + j, u, w);
        return;
    }

    const int seg = t >> 5;
    const int li  = t & 31;
    const int m   = blk * 8 + seg;
    const int v0  = li * 8;
    const size_t base = (size_t)m * 256 + v0;

    const float4 xa = *(const float4*)(x + base);
    const float4 xb = *(const float4*)(x + base + 4);
    const float4 ya = *(const float4*)(y + base);
    const float4 yb = *(const float4*)(y + base + 4);
    const float4 aa = *(const float4*)(av_g + base);
    const float4 ab = *(const float4*)(av_g + base + 4);
    const float4 na = *(const float4*)(xn_g + base);
    const float4 nb = *(const float4*)(xn_g + base + 4);
    const float4 ma = *(const float4*)(yn_g + base);
    const float4 mb = *(const float4*)(yn_g + base + 4);

    PACK8(xh + base, xa, xb);
    PACK8(yh + base, ya, yb);

    float r0 = DOT8(aa, ab, na, nb);
    float r1 = DOT8(aa, ab, ma, mb);
    float r2 = DOT8(na, nb, ma, mb);
    float r3 = DOT8(aa, ab, aa, ab);
    float r4 = DOT8(na, nb, na, nb);
    float r5 = DOT8(ma, mb, ma, mb);
    float r6 = DOT8(xa, xb, xa, xb);
    float r7 = DOT8(ya, yb, ya, yb);
    float r8 = DOT8(xa, xb, ya, yb);
    float r9, r10, r11, r12, r13, r14, r15, r16;
    {
        const float4 d0a = *(const float4*)(def + v0);
        const float4 d0b = *(const float4*)(def + v0 + 4);
        r9  = DOT8(xa, xb, d0a, d0b);  r13 = DOT8(ya, yb, d0a, d0b);
        const float4 d1a = *(const float4*)(def + 256 + v0);
        const float4 d1b = *(const float4*)(def + 256 + v0 + 4);
        r10 = DOT8(xa, xb, d1a, d1b);  r14 = DOT8(ya, yb, d1a, d1b);
        const float4 d2a = *(const float4*)(def + 512 + v0);
        const float4 d2b = *(const float4*)(def + 512 + v0 + 4);
        r11 = DOT8(xa, xb, d2a, d2b);  r15 = DOT8(ya, yb, d2a, d2b);
        const float4 d3a = *(const float4*)(def + 768 + v0);
        const float4 d3b = *(const float4*)(def + 768 + v0 + 4);
        r12 = DOT8(xa, xb, d3a, d3b);  r16 = DOT8(ya, yb, d3a, d3b);
    }
    RED32(r0);  RED32(r1);  RED32(r2);  RED32(r3);  RED32(r4);  RED32(r5);
    RED32(r6);  RED32(r7);  RED32(r8);  RED32(r9);  RED32(r10); RED32(r11);
    RED32(r12); RED32(r13); RED32(r14); RED32(r15); RED32(r16);

    const float nav = fmaxf(sqrtf(r3), EPS);
    const float nxn = fmaxf(sqrtf(r4), EPS);
    const float nyn = fmaxf(sqrtf(r5), EPS);
    float cs[3];
    cs[0] = r0 / (nav * nxn);
    cs[1] = r1 / (nav * nyn);
    cs[2] = r2 / (nxn * nyn);

    float vc[6];
#pragma unroll
    for (int jj = 0; jj < 6; ++jj) {
        float p = 1.0f;
#pragma unroll
        for (int k = 0; k < 3; ++k) {
            const float a = nwv_g[jj * 3 + k];
            p = p * (a * cs[k] + (1.0f - a) * (1.0f - cs[k]));
        }
        vc[jj] = p;
    }

    float val2 = vc[0] * vc[0] * r6 + vc[1] * vc[1] * r7
               + 2.0f * vc[0] * vc[1] * r8;
    const float sx = vc[2] * r9  + vc[3] * r10 + vc[4] * r11 + vc[5] * r12;
    const float sy = vc[2] * r13 + vc[3] * r14 + vc[4] * r15 + vc[5] * r16;
    val2 += 2.0f * vc[0] * sx + 2.0f * vc[1] * sy;
#pragma unroll
    for (int i2 = 0; i2 < 4; ++i2) {
#pragma unroll
        for (int j2 = 0; j2 < 4; ++j2) {
            val2 += vc[2 + i2] * vc[2 + j2] * DD_g[i2 * 4 + j2];
        }
    }
    const float inv_val = 1.0f / fmaxf(sqrtf(val2), EPS);

    if (li == 0) {
        const float4 cA = {vc[0] * inv_val, vc[1] * inv_val,
                           vc[2] * inv_val, vc[3] * inv_val};
        const float4 cB = {vc[4] * inv_val, vc[5] * inv_val, 0.f, 0.f};
        *(float4*)(coef_g + (size_t)m * 8)     = cA;
        *(float4*)(coef_g + (size_t)m * 8 + 4) = cB;
    }
}

// ---------------- K3: PXY GEMM (unchanged from r14) ----------------
__global__ void __launch_bounds__(256) pxy_gemm(
    const __half* __restrict__ xh, const __half* __restrict__ yh,
    const __half* __restrict__ swh, __half* __restrict__ pxy)
{
    const int swz      = (blockIdx.x & 7) * 256 + (blockIdx.x >> 3);
    const int cstrip   = swz & 7;
    const int rowblock = swz >> 3;
    const int wid  = threadIdx.x >> 6;
    const int lane = threadIdx.x & 63;
    const int l16  = lane & 15;
    const int lhi  = lane >> 4;
    const bool isx = rowblock < 128;
    const __half* __restrict__ A = isx ? xh : yh;
    const int row0   = (isx ? rowblock : rowblock - 128) * 256 + wid * 64;
    const int cbase  = cstrip * 32;
    const int colout = isx ? 0 : 256;

    const f32x4 z = {0.f, 0.f, 0.f, 0.f};
    f32x4 acc00 = z, acc01 = z, acc10 = z, acc11 = z;
    f32x4 acc20 = z, acc21 = z, acc30 = z, acc31 = z;

    const __half* arow = A   + (size_t)(row0 + l16) * 256;
    const __half* brow = swh + (size_t)(cbase + l16) * 256;

#pragma unroll
    for (int k0 = 0; k0 < 256; k0 += 32) {
        const int ka = k0 + lhi * 8;
        const half8 a0 = *(const half8*)(arow + ka);
        const half8 a1 = *(const half8*)(arow + 16 * 256 + ka);
        const half8 a2 = *(const half8*)(arow + 32 * 256 + ka);
        const half8 a3 = *(const half8*)(arow + 48 * 256 + ka);
        const half8 b0 = *(const half8*)(brow + ka);
        const half8 b1 = *(const half8*)(brow + 16 * 256 + ka);
        acc00 = __builtin_amdgcn_mfma_f32_16x16x32_f16(a0, b0, acc00, 0, 0, 0);
        acc01 = __builtin_amdgcn_mfma_f32_16x16x32_f16(a0, b1, acc01, 0, 0, 0);
        acc10 = __builtin_amdgcn_mfma_f32_16x16x32_f16(a1, b0, acc10, 0, 0, 0);
        acc11 = __builtin_amdgcn_mfma_f32_16x16x32_f16(a1, b1, acc11, 0, 0, 0);
        acc20 = __builtin_amdgcn_mfma_f32_16x16x32_f16(a2, b0, acc20, 0, 0, 0);
        acc21 = __builtin_amdgcn_mfma_f32_16x16x32_f16(a2, b1, acc21, 0, 0, 0);
        acc30 = __builtin_amdgcn_mfma_f32_16x16x32_f16(a3, b0, acc30, 0, 0, 0);
        acc31 = __builtin_amdgcn_mfma_f32_16x16x32_f16(a3, b1, acc31, 0, 0, 0);
    }

    const int colp = (((colout + cbase) >> 5) << 4) + l16;   // col'
#define STPAIR(ACCA, ACCB, ROFF)                                          \
    do {                                                                  \
        union { fp16x2 p[4]; uint4 u; } pk;                               \
        pk.p[0] = __builtin_amdgcn_cvt_pkrtz((ACCA)[0], (ACCA)[1]);       \
        pk.p[1] = __builtin_amdgcn_cvt_pkrtz((ACCA)[2], (ACCA)[3]);       \
        pk.p[2] = __builtin_amdgcn_cvt_pkrtz((ACCB)[0], (ACCB)[1]);       \
        pk.p[3] = __builtin_amdgcn_cvt_pkrtz((ACCB)[2], (ACCB)[3]);       \
        const size_t hb = (size_t)(((row0 + (ROFF)) >> 2) + lhi) * 2048   \
                        + (size_t)colp * 8;                               \
        *reinterpret_cast<uint4*>(pxy + hb) = pk.u;                       \
    } while (0)
    STPAIR(acc00, acc01, 0);
    STPAIR(acc10, acc11, 16);
    STPAIR(acc20, acc21, 32);
    STPAIR(acc30, acc31, 48);
#undef STPAIR
}

// ---------------- K4: finish-lite (unchanged from r15) ----------------
__device__ __forceinline__ float half_of(uint2 u, int j) {
    const unsigned w = (j < 2) ? u.x : u.y;
    const unsigned sh = (unsigned)(j & 1) * 16u;
    return __half2float(__ushort_as_half((unsigned short)(w >> sh)));
}

__global__ void __launch_bounds__(256) finish_kernel(
    const float* __restrict__ coef_g, const float* __restrict__ PD_g,
    const float* __restrict__ iw1_g, const float* __restrict__ n1_g,
    const __half* __restrict__ pxy, float* __restrict__ i1_g)
{
    const int mg = blockIdx.x;
    const int t = threadIdx.x;

    const int cpx = ((t >> 5) << 4) + (t & 15);
    const int ppx = (t >> 4) & 1;
    const size_t gb = (size_t)mg * 2048;
    const uint2 upx = *reinterpret_cast<const uint2*>(
        pxy + gb + (size_t)cpx * 8 + ppx * 4);
    const uint2 upy = *reinterpret_cast<const uint2*>(
        pxy + gb + (size_t)(128 + cpx) * 8 + ppx * 4);

    const float pd0 = PD_g[t],        pd1 = PD_g[256 + t];
    const float pd2 = PD_g[512 + t],  pd3 = PD_g[768 + t];
    const float iw1v = iw1_g[t];
    const float n1v  = n1_g[t];
    const float An = 2.0f * n1v - 1.0f;
    const float Bn = 1.0f - n1v;

#pragma unroll
    for (int j = 0; j < 4; ++j) {
        const int m = 4 * mg + j;
        const float4 cA = *(const float4*)(coef_g + (size_t)m * 8);
        const float2 cB = *(const float2*)(coef_g + (size_t)m * 8 + 4);
        const float px = half_of(upx, j);
        const float py = half_of(upy, j);
        const float d1s = cA.x * px + cA.y * py
                        + cA.z * pd0 + cA.w * pd1 + cB.x * pd2 + cB.y * pd3;
        float c1 = d1s * iw1v;
        c1 = fmaxf(c1, 0.01f * c1);
        i1_g[(size_t)m * 256 + t] = fmaf(c1, An, Bn);
    }
}

// ---------------- K5: the scan — fp16 dot2, footprint under the cap ----------------
__global__ void __launch_bounds__(64)
__attribute__((amdgpu_waves_per_eu(1, 1)))
scan_kernel(
    const float* __restrict__ i1_g, const unsigned* __restrict__ M0Tp_g,
    const float* __restrict__ G_g, const float* __restrict__ w0s_g,
    const float* __restrict__ iw0_g, const float* __restrict__ n0_g,
    float* __restrict__ gws_g)
{
    const int b = blockIdx.x;
    const int L = threadIdx.x;              // owns c = 4L..4L+3
    const int mcol = L >> 1;                // G/h column (pairs share)

    // M0T fp16 pairs: 16 uint4 = 64 VGPRs (asm loads: cannot be sunk)
#define LW(Q, J) uint4 W##Q##J;                                        \
    asm volatile("global_load_dwordx4 %0, %1, off"                     \
                 : "=v"(W##Q##J)                                       \
                 : "v"(M0Tp_g + ((4 * L + (Q)) * 16 + 4 * (J))));
    LW(0,0) LW(0,1) LW(0,2) LW(0,3)
    LW(1,0) LW(1,1) LW(1,2) LW(1,3)
    LW(2,0) LW(2,1) LW(2,2) LW(2,3)
    LW(3,0) LW(3,1) LW(3,2) LW(3,3)
#undef LW
    // G column fp32 (temporary), packed to 16 fp16-pair VGPRs
#define LGF(K) float gf##K;                                            \
    asm volatile("global_load_dword %0, %1, off"                       \
                 : "=v"(gf##K) : "v"(G_g + (K) * 32 + mcol));
    REP32(LGF)
#undef LGF
    asm volatile("s_waitcnt vmcnt(0)");
    __builtin_amdgcn_sched_barrier(0);
#define PKG(J, A, B) const unsigned GP##J = pk2u(gf##A, gf##B);
    PKG(0, 0, 1)   PKG(1, 2, 3)   PKG(2, 4, 5)   PKG(3, 6, 7)
    PKG(4, 8, 9)   PKG(5, 10, 11) PKG(6, 12, 13) PKG(7, 14, 15)
    PKG(8, 16, 17) PKG(9, 18, 19) PKG(10, 20, 21) PKG(11, 22, 23)
    PKG(12, 24, 25) PKG(13, 26, 27) PKG(14, 28, 29) PKG(15, 30, 31)
#undef PKG

    const float4 w0s4 = *(const float4*)(w0s_g + 4 * L);
    const float4 iw4  = *(const float4*)(iw0_g + 4 * L);
    const float4 n04  = *(const float4*)(n0_g + 4 * L);
    const float4 di = {1e-6f * w0s4.x, 1e-6f * w0s4.y,
                       1e-6f * w0s4.z, 1e-6f * w0s4.w};
    const float4 An = {2.f * n04.x - 1.f, 2.f * n04.y - 1.f,
                       2.f * n04.z - 1.f, 2.f * n04.w - 1.f};
    const float4 Bn = {1.f - n04.x, 1.f - n04.y, 1.f - n04.z, 1.f - n04.w};

    float4 iB = *(const float4*)(i1_g + ((size_t)0 * 256 + b) * 256 + 4 * L);
    float4 iC = *(const float4*)(i1_g + ((size_t)1 * 256 + b) * 256 + 4 * L);

    float gwv;   // loop-carried: lanes 2k,2k+1 hold gw[k]

#define NAND_GW(D0, D1, D2, D3, INV, IC)                              \
    do {                                                              \
        float cc0 = (D0) * (INV) * iw4.x; cc0 = fmaxf(cc0, 0.01f * cc0); \
        float cc1 = (D1) * (INV) * iw4.y; cc1 = fmaxf(cc1, 0.01f * cc1); \
        float cc2 = (D2) * (INV) * iw4.z; cc2 = fmaxf(cc2, 0.01f * cc2); \
        float cc3 = (D3) * (INV) * iw4.w; cc3 = fmaxf(cc3, 0.01f * cc3); \
        const float ch0 = fmaf(cc0, An.x, Bn.x) * (IC).x;             \
        const float ch1 = fmaf(cc1, An.y, Bn.y) * (IC).y;             \
        const float ch2 = fmaf(cc2, An.z, Bn.z) * (IC).z;             \
        const float ch3 = fmaf(cc3, An.w, Bn.w) * (IC).w;             \
        const float s4 = (ch0 + ch1) + (ch2 + ch3);                   \
        gwv = DPP_ADD(s4, 0xB1);  /* quad_perm xor1: pair sum */      \
    } while (0)

    // ---- step 0 ----
    {
        const float inv_rs = 1.0f / fmaxf(sqrtf(2.56e-10f), EPS);
        NAND_GW(di.x, di.y, di.z, di.w, inv_rs, iB);
        if ((L & 1) == 0) gws_g[(size_t)b * 32 + mcol] = gwv;
    }
    iB = iC;

#define DOT2A(ACC, W, S) \
    asm("v_dot2_f32_f16 %0, %1, %2, %0" : "+v"(ACC) : "v"(W), "s"(S));

    for (int s = 1; s < 128; ++s) {
        const int sp = (s + 1 < 128) ? s + 1 : 127;
        const float4 iN = *(const float4*)(
            i1_g + ((size_t)sp * 256 + b) * 256 + 4 * L);

        // pack gw into fp16 pairs, broadcast 16 SGPRs.
        // gwv lanes: 2k,2k+1 = gw[k]; quad_perm [2,3,0,1] (0x4E) brings
        // lane 4j <- lane 4j+2 = gw[2j+1]; pack at lane 4j = (gw[2j],gw[2j+1]).
        const float tsh = DPP_MOVF(gwv, 0x4E);
        const unsigned pg = pk2u(gwv, tsh);
#define RLP(J) const unsigned sg##J = \
        (unsigned)__builtin_amdgcn_readlane((int)pg, 4 * (J));
        REP16(RLP)
#undef RLP

        float d0 = 0.f, d1 = 0.f, d2 = 0.f, d3 = 0.f, h = 0.f;
#define DQ4(ACC, WQJ, S0, S1, S2, S3)        \
        DOT2A(ACC, (WQJ).x, S0)              \
        DOT2A(ACC, (WQJ).y, S1)              \
        DOT2A(ACC, (WQJ).z, S2)              \
        DOT2A(ACC, (WQJ).w, S3)
        DQ4(d0, W00, sg0, sg1, sg2, sg3)   DQ4(d0, W01, sg4, sg5, sg6, sg7)
        DQ4(d0, W02, sg8, sg9, sg10, sg11) DQ4(d0, W03, sg12, sg13, sg14, sg15)
        DQ4(d1, W10, sg0, sg1, sg2, sg3)   DQ4(d1, W11, sg4, sg5, sg6, sg7)
        DQ4(d1, W12, sg8, sg9, sg10, sg11) DQ4(d1, W13, sg12, sg13, sg14, sg15)
        DQ4(d2, W20, sg0, sg1, sg2, sg3)   DQ4(d2, W21, sg4, sg5, sg6, sg7)
        DQ4(d2, W22, sg8, sg9, sg10, sg11) DQ4(d2, W23, sg12, sg13, sg14, sg15)
        DQ4(d3, W30, sg0, sg1, sg2, sg3)   DQ4(d3, W31, sg4, sg5, sg6, sg7)
        DQ4(d3, W32, sg8, sg9, sg10, sg11) DQ4(d3, W33, sg12, sg13, sg14, sg15)
#undef DQ4
        DOT2A(h, GP0, sg0)   DOT2A(h, GP1, sg1)   DOT2A(h, GP2, sg2)
        DOT2A(h, GP3, sg3)   DOT2A(h, GP4, sg4)   DOT2A(h, GP5, sg5)
        DOT2A(h, GP6, sg6)   DOT2A(h, GP7, sg7)   DOT2A(h, GP8, sg8)
        DOT2A(h, GP9, sg9)   DOT2A(h, GP10, sg10) DOT2A(h, GP11, sg11)
        DOT2A(h, GP12, sg12) DOT2A(h, GP13, sg13) DOT2A(h, GP14, sg14)
        DOT2A(h, GP15, sg15)

        float rp = h * gwv;                 // lane L: h[mcol]*gw[mcol]
        rp = DPP_ADD(rp, 0x128);   // row_ror:8
        rp = DPP_ADD(rp, 0x124);   // row_ror:4
        rp = DPP_ADD(rp, 0x122);   // row_ror:2
        rp = DPP_ADD(rp, 0x121);   // row_ror:1
        const float rs2 = 0.5f * (RDLANE(rp, 0) + RDLANE(rp, 16) +
                                  RDLANE(rp, 32) + RDLANE(rp, 48));
        const float inv_rs = 1.0f / fmaxf(sqrtf(rs2), EPS);

        NAND_GW(d0, d1, d2, d3, inv_rs, iB);
        if ((L & 1) == 0)
            gws_g[((size_t)s * 256 + b) * 32 + mcol] = gwv;

        iB = iN;
    }
#undef DOT2A
#undef NAND_GW
}

// ---------------- K6: expand (unchanged) ----------------
__global__ void __launch_bounds__(256) expand_kernel(
    const float* __restrict__ gws_g, const float* __restrict__ sv_g,
    float* __restrict__ out)
{
    const int t = threadIdx.x;
    const int m0 = blockIdx.x * 32;
    __shared__ __align__(16) float SvT[256 * 36];
    __shared__ __align__(16) float gwl[32 * 32];

    for (int i = t; i < 8192; i += 256) {
        const int k = i >> 8, v = i & 255;
        SvT[v * 36 + k] = sv_g[i];
    }
    for (int i = t; i < 1024; i += 256)
        gwl[i] = gws_g[(size_t)m0 * 32 + i];
    __syncthreads();

#pragma unroll 4
    for (int r = 0; r < 32; ++r) {
        float acc = 0.f;
#pragma unroll
        for (int j = 0; j < 8; ++j) {
            const float4 g   = *(const float4*)(gwl + r * 32 + 4 * j);
            const float4 sv4 = *(const float4*)(SvT + t * 36 + 4 * j);
            acc += g.x * sv4.x + g.y * sv4.y + g.z * sv4.z + g.w * sv4.w;
        }
        const int m = m0 + r;
        const int s = m >> 8, bb = m & 255;
        out[((size_t)bb * 128 + s) * 256 + t] = acc;
    }
}

} // namespace

extern "C" void kernel_launch(void* const* d_in, const int* in_sizes, int n_in,
                              void* d_out, int out_size, void* d_ws, size_t ws_size,
                              hipStream_t stream) {
    (void)in_sizes; (void)n_in; (void)out_size; (void)ws_size;
    const float* av  = (const float*)d_in[0];
    const float* xnm = (const float*)d_in[1];
    const float* x   = (const float*)d_in[2];
    const float* ynm = (const float*)d_in[3];
    const float* y   = (const float*)d_in[4];
    const float* sv  = (const float*)d_in[5];
    const float* sw  = (const float*)d_in[6];
    const float* snw = (const float*)d_in[7];
    const float* def = (const float*)d_in[8];
    const float* vnw = (const float*)d_in[9];

    __half* pxy = (__half*)d_ws;
    float*  i1  = (float*)((char*)d_ws + (size_t)33554432);
    float*  gws = i1 + 8388608;
    float*  sm  = gws + 1048576;
    float* M0T = sm;            // 8192
    float* PD  = M0T + 8192;    // 1024
    float* G   = PD + 1024;     // 1024
    float* w0s = G + 1024;      // 256
    float* iw0 = w0s + 256;
    float* iw1 = iw0 + 256;
    float* n0  = iw1 + 256;
    float* n1  = n0 + 256;
    unsigned* M0Tp = (unsigned*)(n1 + 256);  // 4096 uints (fp16 pair layout)
    __half* swh  = (__half*)(M0Tp + 4096);   // 65536 halfs (W1 fp16)
    float* nwvS  = (float*)(swh + 65536);
    float* DDs   = nwvS + 32;
    float* coef  = DDs + 32;
    __half* xh = (__half*)i1;                // alias: dead after pxy_gemm
    __half* yh = xh + 8388608;

    prep_kernel<<<dim3(289), dim3(256), 0, stream>>>(
        sv, sw, snw, def, vnw, M0T, M0Tp, PD, G, w0s, iw0, iw1, n0, n1,
        nwvS, DDs);
    stats_kernel<<<dim3(4128), dim3(256), 0, stream>>>(
        x, y, av, xnm, ynm, def, sw, nwvS, DDs, xh, yh, swh, coef);
    pxy_gemm<<<dim3(2048), dim3(256), 0, stream>>>(xh, yh, swh, pxy);
    finish_kernel<<<dim3(8192), dim3(256), 0, stream>>>(
        coef, PD, iw1, n1, pxy, i1);
    scan_kernel<<<dim3(256), dim3(64), 0, stream>>>(
        i1, M0Tp, G, w0s, iw0, n0, gws);
    expand_kernel<<<dim3(1024), dim3(256), 0, stream>>>(gws, sv, (float*)d_out);
}

// Round 18
// 192.450 us; speedup vs baseline: 1.1045x; 1.0025x over previous
//
#include <hip/hip_runtime.h>
#include <hip/hip_fp16.h>
#include <math.h>

// Round 18: two fixes from r17's profile (stats 65.6us, scan 65.4us):
//  - scan: r17 silently dropped i1 prefetch to depth-1 -> ~600cy vmcnt stall
//    per step (1224cy/step vs ~320 issue floor). Restore depth-3 rotation.
//  - stats: 17 reductions (85 dependent ds_bpermute) -> 7 reductions:
//    reds r0..r5 -> uniform vc -> ELEMENTWISE val (r14-style) -> 1 red of
//    |val|^2. Each red = 4 DPP row_ror adds + 1 shfl_xor(16) (fast VALU).
// Everything else unchanged from r17 (absmax 1.953e-3 preserved).

namespace {

constexpr float EPS = 1e-8f;

typedef _Float16 half8  __attribute__((ext_vector_type(8)));
typedef __fp16   fp16x2 __attribute__((ext_vector_type(2)));
typedef float    f32x4  __attribute__((ext_vector_type(4)));

__device__ __forceinline__ float sigmoidf_(float x) {
    return 1.0f / (1.0f + expf(-x));
}

#define RTREE64(p) do { \
    p += __shfl_xor(p, 32); p += __shfl_xor(p, 16); p += __shfl_xor(p, 8); \
    p += __shfl_xor(p, 4);  p += __shfl_xor(p, 2);  p += __shfl_xor(p, 1); } while (0)

#define DPP_ADD(x, CTRL) \
    ((x) + __int_as_float(__builtin_amdgcn_mov_dpp( \
        __float_as_int(x), (CTRL), 0xF, 0xF, true)))
#define DPP_MOVF(x, CTRL) \
    __int_as_float(__builtin_amdgcn_mov_dpp(__float_as_int(x), (CTRL), 0xF, 0xF, true))
#define RDLANE(x, L) \
    __int_as_float(__builtin_amdgcn_readlane(__float_as_int(x), (L)))

// 32-lane segmented reduce: 4 DPP row_ror adds (full 16-row sum, all lanes)
// + 1 shfl_xor(16) to combine the two rows. All 32 lanes get the total.
#define RED32F(p) do { \
    p = DPP_ADD(p, 0x128); p = DPP_ADD(p, 0x124); \
    p = DPP_ADD(p, 0x122); p = DPP_ADD(p, 0x121); \
    p += __shfl_xor(p, 16); } while (0)

#define REP32(F) F(0) F(1) F(2) F(3) F(4) F(5) F(6) F(7) \
                 F(8) F(9) F(10) F(11) F(12) F(13) F(14) F(15) \
                 F(16) F(17) F(18) F(19) F(20) F(21) F(22) F(23) \
                 F(24) F(25) F(26) F(27) F(28) F(29) F(30) F(31)
#define REP16(F) F(0) F(1) F(2) F(3) F(4) F(5) F(6) F(7) \
                 F(8) F(9) F(10) F(11) F(12) F(13) F(14) F(15)

#define DOT8(A0, A1, B0, B1) \
    ((A0).x * (B0).x + (A0).y * (B0).y + (A0).z * (B0).z + (A0).w * (B0).w + \
     (A1).x * (B1).x + (A1).y * (B1).y + (A1).z * (B1).z + (A1).w * (B1).w)

#define PACK8(DST, U, W)                                           \
    do {                                                           \
        union { fp16x2 p[4]; uint4 q; } pk_;                       \
        pk_.p[0] = __builtin_amdgcn_cvt_pkrtz((U).x, (U).y);       \
        pk_.p[1] = __builtin_amdgcn_cvt_pkrtz((U).z, (U).w);       \
        pk_.p[2] = __builtin_amdgcn_cvt_pkrtz((W).x, (W).y);       \
        pk_.p[3] = __builtin_amdgcn_cvt_pkrtz((W).z, (W).w);       \
        *reinterpret_cast<uint4*>(DST) = pk_.q;                    \
    } while (0)

__device__ __forceinline__ unsigned pk2u(float a, float b) {
    union { fp16x2 p; unsigned u; } cv;
    cv.p = __builtin_amdgcn_cvt_pkrtz(a, b);
    return cv.u;
}

// ---------------- K1: prep (unchanged from r17) ----------------
__global__ void __launch_bounds__(256) prep_kernel(
    const float* __restrict__ sv, const float* __restrict__ sw,
    const float* __restrict__ snw, const float* __restrict__ def,
    const float* __restrict__ vnw,
    float* __restrict__ M0T, unsigned* __restrict__ M0Tp,
    float* __restrict__ PD, float* __restrict__ G,
    float* __restrict__ w0s, float* __restrict__ iw0, float* __restrict__ iw1,
    float* __restrict__ n0, float* __restrict__ n1,
    float* __restrict__ nwv_g, float* __restrict__ DD_g)
{
    const int t = threadIdx.x, wave = t >> 6, lane = t & 63;
    __shared__ float wsum[39][4];

    if (blockIdx.x < 256) {
        const int c = blockIdx.x;
        const float w0v = sw[(size_t)c * 512 + t];
        const float w1v = sw[(size_t)c * 512 + 256 + t];
#pragma unroll
        for (int k = 0; k < 32; ++k) {
            float p = w0v * sv[k * 256 + t];
            RTREE64(p);
            if (lane == 0) wsum[k][wave] = p;
        }
#pragma unroll
        for (int j = 0; j < 4; ++j) {
            float p = w1v * def[j * 256 + t];
            RTREE64(p);
            if (lane == 0) wsum[32 + j][wave] = p;
        }
        {
            float p = w0v * w0v; RTREE64(p); if (lane == 0) wsum[36][wave] = p;
            float q = w1v * w1v; RTREE64(q); if (lane == 0) wsum[37][wave] = q;
            float r = w0v;       RTREE64(r); if (lane == 0) wsum[38][wave] = r;
        }
        __syncthreads();
        if (t < 32) {
            const float v = wsum[t][0] + wsum[t][1] + wsum[t][2] + wsum[t][3];
            M0T[t * 256 + c] = v;
            const float vn = __shfl_down(v, 1);   // valid at even t
            if ((t & 1) == 0)
                M0Tp[c * 16 + (t >> 1)] = pk2u(v, vn);
        } else if (t < 36) {
            PD[(t - 32) * 256 + c] =
                wsum[t][0] + wsum[t][1] + wsum[t][2] + wsum[t][3];
        } else if (t == 36) {
            iw0[c] = 1.0f / fmaxf(sqrtf(wsum[36][0] + wsum[36][1] +
                                        wsum[36][2] + wsum[36][3]), EPS);
        } else if (t == 37) {
            iw1[c] = 1.0f / fmaxf(sqrtf(wsum[37][0] + wsum[37][1] +
                                        wsum[37][2] + wsum[37][3]), EPS);
        } else if (t == 38) {
            w0s[c] = wsum[38][0] + wsum[38][1] + wsum[38][2] + wsum[38][3];
        } else if (t == 39) {
            n0[c] = sigmoidf_(snw[2 * c]);
        } else if (t == 40) {
            n1[c] = sigmoidf_(snw[2 * c + 1]);
        }
    } else if (blockIdx.x < 288) {
        const int k = blockIdx.x - 256;
        const float svk = sv[k * 256 + t];
#pragma unroll
        for (int m = 0; m < 32; ++m) {
            float p = svk * sv[m * 256 + t];
            RTREE64(p);
            if (lane == 0) wsum[m][wave] = p;
        }
        __syncthreads();
        if (t < 32)
            G[k * 32 + t] = wsum[t][0] + wsum[t][1] + wsum[t][2] + wsum[t][3];
    } else {
        if (t < 18) nwv_g[t] = sigmoidf_(vnw[t]);
        if (t < 16) DD_g[t] = 0.f;   // unused now
    }
}

// ---------------- K2: stats + cvt — 7 reductions, elementwise val ----------------
__global__ void __launch_bounds__(256) stats_kernel(
    const float* __restrict__ x, const float* __restrict__ y,
    const float* __restrict__ av_g, const float* __restrict__ xn_g,
    const float* __restrict__ yn_g, const float* __restrict__ def,
    const float* __restrict__ sw, const float* __restrict__ nwv_g,
    const float* __restrict__ DD_g,
    __half* __restrict__ xh, __half* __restrict__ yh,
    __half* __restrict__ swh, float* __restrict__ coef_g)
{
    (void)DD_g;
    const int blk = blockIdx.x;
    const int t   = threadIdx.x;

    if (blk >= 4096) {   // sw (k=1) fp16 tail
        const size_t j = ((size_t)(blk - 4096) * 256 + t) * 8;
        const int c = (int)(j >> 8), k = (int)(j & 255);
        const float* src = sw + (size_t)c * 512 + 256 + k;
        const float4 u = *(const float4*)(src);
        const float4 w = *(const float4*)(src + 4);
        PACK8(swh + j, u, w);
        return;
    }

    const int seg = t >> 5;
    const int li  = t & 31;
    const int m   = blk * 8 + seg;
    const int v0  = li * 8;
    const size_t base = (size_t)m * 256 + v0;

    const float4 xa = *(const float4*)(x + base);
    const float4 xb = *(const float4*)(x + base + 4);
    const float4 ya = *(const float4*)(y + base);
    const float4 yb = *(const float4*)(y + base + 4);
    const float4 aa = *(const float4*)(av_g + base);
    const float4 ab = *(const float4*)(av_g + base + 4);
    const float4 na = *(const float4*)(xn_g + base);
    const float4 nb = *(const float4*)(xn_g + base + 4);
    const float4 ma = *(const float4*)(yn_g + base);
    const float4 mb = *(const float4*)(yn_g + base + 4);

    PACK8(xh + base, xa, xb);
    PACK8(yh + base, ya, yb);

    float r0 = DOT8(aa, ab, na, nb);   // av.xn
    float r1 = DOT8(aa, ab, ma, mb);   // av.yn
    float r2 = DOT8(na, nb, ma, mb);   // xn.yn
    float r3 = DOT8(aa, ab, aa, ab);   // |av|^2
    float r4 = DOT8(na, nb, na, nb);   // |xn|^2
    float r5 = DOT8(ma, mb, ma, mb);   // |yn|^2
    RED32F(r0); RED32F(r1); RED32F(r2);
    RED32F(r3); RED32F(r4); RED32F(r5);

    const float nav = fmaxf(sqrtf(r3), EPS);
    const float nxn = fmaxf(sqrtf(r4), EPS);
    const float nyn = fmaxf(sqrtf(r5), EPS);
    float cs[3];
    cs[0] = r0 / (nav * nxn);
    cs[1] = r1 / (nav * nyn);
    cs[2] = r2 / (nxn * nyn);

    float vc[6];
#pragma unroll
    for (int jj = 0; jj < 6; ++jj) {
        float p = 1.0f;
#pragma unroll
        for (int k = 0; k < 3; ++k) {
            const float a = nwv_g[jj * 3 + k];
            p = p * (a * cs[k] + (1.0f - a) * (1.0f - cs[k]));
        }
        vc[jj] = p;
    }

    // elementwise val for this lane's 8 components, then one |val|^2 reduce
    const float4 d0a = *(const float4*)(def + v0);
    const float4 d0b = *(const float4*)(def + v0 + 4);
    const float4 d1a = *(const float4*)(def + 256 + v0);
    const float4 d1b = *(const float4*)(def + 256 + v0 + 4);
    const float4 d2a = *(const float4*)(def + 512 + v0);
    const float4 d2b = *(const float4*)(def + 512 + v0 + 4);
    const float4 d3a = *(const float4*)(def + 768 + v0);
    const float4 d3b = *(const float4*)(def + 768 + v0 + 4);

    float val2 = 0.f;
#define VALC(COMP, XA, YA, D0, D1, D2, D3)                           \
    do {                                                             \
        const float v_ = vc[0] * (XA).COMP + vc[1] * (YA).COMP       \
                       + vc[2] * (D0).COMP + vc[3] * (D1).COMP       \
                       + vc[4] * (D2).COMP + vc[5] * (D3).COMP;      \
        val2 = fmaf(v_, v_, val2);                                   \
    } while (0)
    VALC(x, xa, ya, d0a, d1a, d2a, d3a);
    VALC(y, xa, ya, d0a, d1a, d2a, d3a);
    VALC(z, xa, ya, d0a, d1a, d2a, d3a);
    VALC(w, xa, ya, d0a, d1a, d2a, d3a);
    VALC(x, xb, yb, d0b, d1b, d2b, d3b);
    VALC(y, xb, yb, d0b, d1b, d2b, d3b);
    VALC(z, xb, yb, d0b, d1b, d2b, d3b);
    VALC(w, xb, yb, d0b, d1b, d2b, d3b);
#undef VALC
    RED32F(val2);
    const float inv_val = 1.0f / fmaxf(sqrtf(val2), EPS);

    if (li == 0) {
        const float4 cA = {vc[0] * inv_val, vc[1] * inv_val,
                           vc[2] * inv_val, vc[3] * inv_val};
        const float4 cB = {vc[4] * inv_val, vc[5] * inv_val, 0.f, 0.f};
        *(float4*)(coef_g + (size_t)m * 8)     = cA;
        *(float4*)(coef_g + (size_t)m * 8 + 4) = cB;
    }
}

// ---------------- K3: PXY GEMM (unchanged from r14) ----------------
__global__ void __launch_bounds__(256) pxy_gemm(
    const __half* __restrict__ xh, const __half* __restrict__ yh,
    const __half* __restrict__ swh, __half* __restrict__ pxy)
{
    const int swz      = (blockIdx.x & 7) * 256 + (blockIdx.x >> 3);
    const int cstrip   = swz & 7;
    const int rowblock = swz >> 3;
    const int wid  = threadIdx.x >> 6;
    const int lane = threadIdx.x & 63;
    const int l16  = lane & 15;
    const int lhi  = lane >> 4;
    const bool isx = rowblock < 128;
    const __half* __restrict__ A = isx ? xh : yh;
    const int row0   = (isx ? rowblock : rowblock - 128) * 256 + wid * 64;
    const int cbase  = cstrip * 32;
    const int colout = isx ? 0 : 256;

    const f32x4 z = {0.f, 0.f, 0.f, 0.f};
    f32x4 acc00 = z, acc01 = z, acc10 = z, acc11 = z;
    f32x4 acc20 = z, acc21 = z, acc30 = z, acc31 = z;

    const __half* arow = A   + (size_t)(row0 + l16) * 256;
    const __half* brow = swh + (size_t)(cbase + l16) * 256;

#pragma unroll
    for (int k0 = 0; k0 < 256; k0 += 32) {
        const int ka = k0 + lhi * 8;
        const half8 a0 = *(const half8*)(arow + ka);
        const half8 a1 = *(const half8*)(arow + 16 * 256 + ka);
        const half8 a2 = *(const half8*)(arow + 32 * 256 + ka);
        const half8 a3 = *(const half8*)(arow + 48 * 256 + ka);
        const half8 b0 = *(const half8*)(brow + ka);
        const half8 b1 = *(const half8*)(brow + 16 * 256 + ka);
        acc00 = __builtin_amdgcn_mfma_f32_16x16x32_f16(a0, b0, acc00, 0, 0, 0);
        acc01 = __builtin_amdgcn_mfma_f32_16x16x32_f16(a0, b1, acc01, 0, 0, 0);
        acc10 = __builtin_amdgcn_mfma_f32_16x16x32_f16(a1, b0, acc10, 0, 0, 0);
        acc11 = __builtin_amdgcn_mfma_f32_16x16x32_f16(a1, b1, acc11, 0, 0, 0);
        acc20 = __builtin_amdgcn_mfma_f32_16x16x32_f16(a2, b0, acc20, 0, 0, 0);
        acc21 = __builtin_amdgcn_mfma_f32_16x16x32_f16(a2, b1, acc21, 0, 0, 0);
        acc30 = __builtin_amdgcn_mfma_f32_16x16x32_f16(a3, b0, acc30, 0, 0, 0);
        acc31 = __builtin_amdgcn_mfma_f32_16x16x32_f16(a3, b1, acc31, 0, 0, 0);
    }

    const int colp = (((colout + cbase) >> 5) << 4) + l16;   // col'
#define STPAIR(ACCA, ACCB, ROFF)                                          \
    do {                                                                  \
        union { fp16x2 p[4]; uint4 u; } pk;                               \
        pk.p[0] = __builtin_amdgcn_cvt_pkrtz((ACCA)[0], (ACCA)[1]);       \
        pk.p[1] = __builtin_amdgcn_cvt_pkrtz((ACCA)[2], (ACCA)[3]);       \
        pk.p[2] = __builtin_amdgcn_cvt_pkrtz((ACCB)[0], (ACCB)[1]);       \
        pk.p[3] = __builtin_amdgcn_cvt_pkrtz((ACCB)[2], (ACCB)[3]);       \
        const size_t hb = (size_t)(((row0 + (ROFF)) >> 2) + lhi) * 2048   \
                        + (size_t)colp * 8;                               \
        *reinterpret_cast<uint4*>(pxy + hb) = pk.u;                       \
    } while (0)
    STPAIR(acc00, acc01, 0);
    STPAIR(acc10, acc11, 16);
    STPAIR(acc20, acc21, 32);
    STPAIR(acc30, acc31, 48);
#undef STPAIR
}

// ---------------- K4: finish-lite (unchanged from r15) ----------------
__device__ __forceinline__ float half_of(uint2 u, int j) {
    const unsigned w = (j < 2) ? u.x : u.y;
    const unsigned sh = (unsigned)(j & 1) * 16u;
    return __half2float(__ushort_as_half((unsigned short)(w >> sh)));
}

__global__ void __launch_bounds__(256) finish_kernel(
    const float* __restrict__ coef_g, const float* __restrict__ PD_g,
    const float* __restrict__ iw1_g, const float* __restrict__ n1_g,
    const __half* __restrict__ pxy, float* __restrict__ i1_g)
{
    const int mg = blockIdx.x;
    const int t = threadIdx.x;

    const int cpx = ((t >> 5) << 4) + (t & 15);
    const int ppx = (t >> 4) & 1;
    const size_t gb = (size_t)mg * 2048;
    const uint2 upx = *reinterpret_cast<const uint2*>(
        pxy + gb + (size_t)cpx * 8 + ppx * 4);
    const uint2 upy = *reinterpret_cast<const uint2*>(
        pxy + gb + (size_t)(128 + cpx) * 8 + ppx * 4);

    const float pd0 = PD_g[t],        pd1 = PD_g[256 + t];
    const float pd2 = PD_g[512 + t],  pd3 = PD_g[768 + t];
    const float iw1v = iw1_g[t];
    const float n1v  = n1_g[t];
    const float An = 2.0f * n1v - 1.0f;
    const float Bn = 1.0f - n1v;

#pragma unroll
    for (int j = 0; j < 4; ++j) {
        const int m = 4 * mg + j;
        const float4 cA = *(const float4*)(coef_g + (size_t)m * 8);
        const float2 cB = *(const float2*)(coef_g + (size_t)m * 8 + 4);
        const float px = half_of(upx, j);
        const float py = half_of(upy, j);
        const float d1s = cA.x * px + cA.y * py
                        + cA.z * pd0 + cA.w * pd1 + cB.x * pd2 + cB.y * pd3;
        float c1 = d1s * iw1v;
        c1 = fmaxf(c1, 0.01f * c1);
        i1_g[(size_t)m * 256 + t] = fmaf(c1, An, Bn);
    }
}

// ---------------- K5: the scan — fp16 dot2, depth-3 i1 prefetch ----------------
__global__ void __launch_bounds__(64)
__attribute__((amdgpu_waves_per_eu(1, 1)))
scan_kernel(
    const float* __restrict__ i1_g, const unsigned* __restrict__ M0Tp_g,
    const float* __restrict__ G_g, const float* __restrict__ w0s_g,
    const float* __restrict__ iw0_g, const float* __restrict__ n0_g,
    float* __restrict__ gws_g)
{
    const int b = blockIdx.x;
    const int L = threadIdx.x;              // owns c = 4L..4L+3
    const int mcol = L >> 1;                // G/h column (pairs share)

#define LW(Q, J) uint4 W##Q##J;                                        \
    asm volatile("global_load_dwordx4 %0, %1, off"                     \
                 : "=v"(W##Q##J)                                       \
                 : "v"(M0Tp_g + ((4 * L + (Q)) * 16 + 4 * (J))));
    LW(0,0) LW(0,1) LW(0,2) LW(0,3)
    LW(1,0) LW(1,1) LW(1,2) LW(1,3)
    LW(2,0) LW(2,1) LW(2,2) LW(2,3)
    LW(3,0) LW(3,1) LW(3,2) LW(3,3)
#undef LW
#define LGF(K) float gf##K;                                            \
    asm volatile("global_load_dword %0, %1, off"                       \
                 : "=v"(gf##K) : "v"(G_g + (K) * 32 + mcol));
    REP32(LGF)
#undef LGF
    asm volatile("s_waitcnt vmcnt(0)");
    __builtin_amdgcn_sched_barrier(0);
#define PKG(J, A, B) const unsigned GP##J = pk2u(gf##A, gf##B);
    PKG(0, 0, 1)   PKG(1, 2, 3)   PKG(2, 4, 5)   PKG(3, 6, 7)
    PKG(4, 8, 9)   PKG(5, 10, 11) PKG(6, 12, 13) PKG(7, 14, 15)
    PKG(8, 16, 17) PKG(9, 18, 19) PKG(10, 20, 21) PKG(11, 22, 23)
    PKG(12, 24, 25) PKG(13, 26, 27) PKG(14, 28, 29) PKG(15, 30, 31)
#undef PKG

    const float4 w0s4 = *(const float4*)(w0s_g + 4 * L);
    const float4 iw4  = *(const float4*)(iw0_g + 4 * L);
    const float4 n04  = *(const float4*)(n0_g + 4 * L);
    const float4 di = {1e-6f * w0s4.x, 1e-6f * w0s4.y,
                       1e-6f * w0s4.z, 1e-6f * w0s4.w};
    const float4 An = {2.f * n04.x - 1.f, 2.f * n04.y - 1.f,
                       2.f * n04.z - 1.f, 2.f * n04.w - 1.f};
    const float4 Bn = {1.f - n04.x, 1.f - n04.y, 1.f - n04.z, 1.f - n04.w};

    // i1 prefetch pipeline, depth 3
    float4 iA = *(const float4*)(i1_g + ((size_t)0 * 256 + b) * 256 + 4 * L);
    float4 iB = *(const float4*)(i1_g + ((size_t)1 * 256 + b) * 256 + 4 * L);
    float4 iC = *(const float4*)(i1_g + ((size_t)2 * 256 + b) * 256 + 4 * L);
    float4 iD = *(const float4*)(i1_g + ((size_t)3 * 256 + b) * 256 + 4 * L);

    float gwv;   // loop-carried: lanes 2k,2k+1 hold gw[k]

#define NAND_GW(D0, D1, D2, D3, INV, IC)                              \
    do {                                                              \
        float cc0 = (D0) * (INV) * iw4.x; cc0 = fmaxf(cc0, 0.01f * cc0); \
        float cc1 = (D1) * (INV) * iw4.y; cc1 = fmaxf(cc1, 0.01f * cc1); \
        float cc2 = (D2) * (INV) * iw4.z; cc2 = fmaxf(cc2, 0.01f * cc2); \
        float cc3 = (D3) * (INV) * iw4.w; cc3 = fmaxf(cc3, 0.01f * cc3); \
        const float ch0 = fmaf(cc0, An.x, Bn.x) * (IC).x;             \
        const float ch1 = fmaf(cc1, An.y, Bn.y) * (IC).y;             \
        const float ch2 = fmaf(cc2, An.z, Bn.z) * (IC).z;             \
        const float ch3 = fmaf(cc3, An.w, Bn.w) * (IC).w;             \
        const float s4 = (ch0 + ch1) + (ch2 + ch3);                   \
        gwv = DPP_ADD(s4, 0xB1);  /* quad_perm xor1: pair sum */      \
    } while (0)

    // ---- step 0 ----
    {
        const float inv_rs = 1.0f / fmaxf(sqrtf(2.56e-10f), EPS);
        NAND_GW(di.x, di.y, di.z, di.w, inv_rs, iA);
        if ((L & 1) == 0) gws_g[(size_t)b * 32 + mcol] = gwv;
    }

#define DOT2A(ACC, W, S) \
    asm("v_dot2_f32_f16 %0, %1, %2, %0" : "+v"(ACC) : "v"(W), "s"(S));

    for (int s = 1; s < 128; ++s) {
        const int sp = (s + 3 < 128) ? s + 3 : 127;
        const float4 iN = *(const float4*)(
            i1_g + ((size_t)sp * 256 + b) * 256 + 4 * L);

        // pack gw into fp16 pairs, broadcast 16 SGPRs
        const float tsh = DPP_MOVF(gwv, 0x4E);
        const unsigned pg = pk2u(gwv, tsh);
#define RLP(J) const unsigned sg##J = \
        (unsigned)__builtin_amdgcn_readlane((int)pg, 4 * (J));
        REP16(RLP)
#undef RLP

        float d0 = 0.f, d1 = 0.f, d2 = 0.f, d3 = 0.f, h = 0.f;
#define DQ4(ACC, WQJ, S0, S1, S2, S3)        \
        DOT2A(ACC, (WQJ).x, S0)              \
        DOT2A(ACC, (WQJ).y, S1)              \
        DOT2A(ACC, (WQJ).z, S2)              \
        DOT2A(ACC, (WQJ).w, S3)
        DQ4(d0, W00, sg0, sg1, sg2, sg3)   DQ4(d0, W01, sg4, sg5, sg6, sg7)
        DQ4(d0, W02, sg8, sg9, sg10, sg11) DQ4(d0, W03, sg12, sg13, sg14, sg15)
        DQ4(d1, W10, sg0, sg1, sg2, sg3)   DQ4(d1, W11, sg4, sg5, sg6, sg7)
        DQ4(d1, W12, sg8, sg9, sg10, sg11) DQ4(d1, W13, sg12, sg13, sg14, sg15)
        DQ4(d2, W20, sg0, sg1, sg2, sg3)   DQ4(d2, W21, sg4, sg5, sg6, sg7)
        DQ4(d2, W22, sg8, sg9, sg10, sg11) DQ4(d2, W23, sg12, sg13, sg14, sg15)
        DQ4(d3, W30, sg0, sg1, sg2, sg3)   DQ4(d3, W31, sg4, sg5, sg6, sg7)
        DQ4(d3, W32, sg8, sg9, sg10, sg11) DQ4(d3, W33, sg12, sg13, sg14, sg15)
#undef DQ4
        DOT2A(h, GP0, sg0)   DOT2A(h, GP1, sg1)   DOT2A(h, GP2, sg2)
        DOT2A(h, GP3, sg3)   DOT2A(h, GP4, sg4)   DOT2A(h, GP5, sg5)
        DOT2A(h, GP6, sg6)   DOT2A(h, GP7, sg7)   DOT2A(h, GP8, sg8)
        DOT2A(h, GP9, sg9)   DOT2A(h, GP10, sg10) DOT2A(h, GP11, sg11)
        DOT2A(h, GP12, sg12) DOT2A(h, GP13, sg13) DOT2A(h, GP14, sg14)
        DOT2A(h, GP15, sg15)

        float rp = h * gwv;                 // lane L: h[mcol]*gw[mcol]
        rp = DPP_ADD(rp, 0x128);   // row_ror:8
        rp = DPP_ADD(rp, 0x124);   // row_ror:4
        rp = DPP_ADD(rp, 0x122);   // row_ror:2
        rp = DPP_ADD(rp, 0x121);   // row_ror:1
        const float rs2 = 0.5f * (RDLANE(rp, 0) + RDLANE(rp, 16) +
                                  RDLANE(rp, 32) + RDLANE(rp, 48));
        const float inv_rs = 1.0f / fmaxf(sqrtf(rs2), EPS);

        NAND_GW(d0, d1, d2, d3, inv_rs, iB);
        if ((L & 1) == 0)
            gws_g[((size_t)s * 256 + b) * 32 + mcol] = gwv;

        iB = iC; iC = iD; iD = iN;
    }
#undef DOT2A
#undef NAND_GW
}

// ---------------- K6: expand (unchanged) ----------------
__global__ void __launch_bounds__(256) expand_kernel(
    const float* __restrict__ gws_g, const float* __restrict__ sv_g,
    float* __restrict__ out)
{
    const int t = threadIdx.x;
    const int m0 = blockIdx.x * 32;
    __shared__ __align__(16) float SvT[256 * 36];
    __shared__ __align__(16) float gwl[32 * 32];

    for (int i = t; i < 8192; i += 256) {
        const int k = i >> 8, v = i & 255;
        SvT[v * 36 + k] = sv_g[i];
    }
    for (int i = t; i < 1024; i += 256)
        gwl[i] = gws_g[(size_t)m0 * 32 + i];
    __syncthreads();

#pragma unroll 4
    for (int r = 0; r < 32; ++r) {
        float acc = 0.f;
#pragma unroll
        for (int j = 0; j < 8; ++j) {
            const float4 g   = *(const float4*)(gwl + r * 32 + 4 * j);
            const float4 sv4 = *(const float4*)(SvT + t * 36 + 4 * j);
            acc += g.x * sv4.x + g.y * sv4.y + g.z * sv4.z + g.w * sv4.w;
        }
        const int m = m0 + r;
        const int s = m >> 8, bb = m & 255;
        out[((size_t)bb * 128 + s) * 256 + t] = acc;
    }
}

} // namespace

extern "C" void kernel_launch(void* const* d_in, const int* in_sizes, int n_in,
                              void* d_out, int out_size, void* d_ws, size_t ws_size,
                              hipStream_t stream) {
    (void)in_sizes; (void)n_in; (void)out_size; (void)ws_size;
    const float* av  = (const float*)d_in[0];
    const float* xnm = (const float*)d_in[1];
    const float* x   = (const float*)d_in[2];
    const float* ynm = (const float*)d_in[3];
    const float* y   = (const float*)d_in[4];
    const float* sv  = (const float*)d_in[5];
    const float* sw  = (const float*)d_in[6];
    const float* snw = (const float*)d_in[7];
    const float* def = (const float*)d_in[8];
    const float* vnw = (const float*)d_in[9];

    __half* pxy = (__half*)d_ws;
    float*  i1  = (float*)((char*)d_ws + (size_t)33554432);
    float*  gws = i1 + 8388608;
    float*  sm  = gws + 1048576;
    float* M0T = sm;            // 8192
    float* PD  = M0T + 8192;    // 1024
    float* G   = PD + 1024;     // 1024
    float* w0s = G + 1024;      // 256
    float* iw0 = w0s + 256;
    float* iw1 = iw0 + 256;
    float* n0  = iw1 + 256;
    float* n1  = n0 + 256;
    unsigned* M0Tp = (unsigned*)(n1 + 256);  // 4096 uints (fp16 pair layout)
    __half* swh  = (__half*)(M0Tp + 4096);   // 65536 halfs (W1 fp16)
    float* nwvS  = (float*)(swh + 65536);
    float* DDs   = nwvS + 32;
    float* coef  = DDs + 32;
    __half* xh = (__half*)i1;                // alias: dead after pxy_gemm
    __half* yh = xh + 8388608;

    prep_kernel<<<dim3(289), dim3(256), 0, stream>>>(
        sv, sw, snw, def, vnw, M0T, M0Tp, PD, G, w0s, iw0, iw1, n0, n1,
        nwvS, DDs);
    stats_kernel<<<dim3(4128), dim3(256), 0, stream>>>(
        x, y, av, xnm, ynm, def, sw, nwvS, DDs, xh, yh, swh, coef);
    pxy_gemm<<<dim3(2048), dim3(256), 0, stream>>>(xh, yh, swh, pxy);
    finish_kernel<<<dim3(8192), dim3(256), 0, stream>>>(
        coef, PD, iw1, n1, pxy, i1);
    scan_kernel<<<dim3(256), dim3(64), 0, stream>>>(
        i1, M0Tp, G, w0s, iw0, n0, gws);
    expand_kernel<<<dim3(1024), dim3(256), 0, stream>>>(gws, sv, (float*)d_out);
}